// Round 7
// baseline (643.608 us; speedup 1.0000x reference)
//
#include <hip/hip_runtime.h>
#include <hip/hip_bf16.h>
#include <math.h>

#define H 256
#define N0 50000
#define N1 10000
#define N2 4000
#define N3 1024
#define FAN 16

typedef __hip_bfloat16 bf16;
typedef __attribute__((ext_vector_type(8))) short short8;
typedef __attribute__((ext_vector_type(4))) short short4v;
typedef __attribute__((ext_vector_type(2))) short short2v;
typedef __attribute__((ext_vector_type(4))) float floatx4;

typedef const __attribute__((address_space(1))) void* gas_ptr;
typedef __attribute__((address_space(3))) void* las_ptr;

__device__ __forceinline__ void load_lds16(const void* g, void* l) {
    __builtin_amdgcn_global_load_lds((gas_ptr)g, (las_ptr)l, 16, 0, 0);
}

__device__ __forceinline__ float2 cvt_bf2(unsigned u) {
    union { unsigned q; float f; } lo, hi;
    lo.q = u << 16; hi.q = u & 0xffff0000u;
    return make_float2(lo.f, hi.f);
}

// ---------------- dual-output LDS-A MFMA GEMM ----------------
// One dispatch computes BOTH the kv GEMM (bf16 out) and qs GEMM (fp32 out):
// grid.x < nbKV -> kv blocks, else qs blocks. Tile 64 rows x 256 cols, 256 thr.
// GATHER=true (L1): A rows gathered from fp32 features via idx, converted to
// bf16 in registers, staged to LDS with XOR chunk swizzle (no Xg round-trip).
// GATHER=false: A already bf16; staged via global_load_lds (16B, XOR swizzle).
// No K-loop barriers; B from L2-resident global with one-step reg prefetch.
template<int K, bool GATHER>
__global__ __launch_bounds__(256, GATHER ? 4 : 5) void gemm_dual(
    const void* __restrict__ Asrc, size_t Astr,
    const int* __restrict__ idx, size_t idxStr,
    const bf16* __restrict__ BtKV, const bf16* __restrict__ BtQS,
    const float* __restrict__ bk, const float* __restrict__ bv,
    const float* __restrict__ bq, const float* __restrict__ bs, int Nh,
    bf16* __restrict__ Ckv, size_t CkvStr, int Mkv,
    float* __restrict__ Cqs, size_t CqsStr, int Mqs,
    int nbKV)
{
    constexpr int KC = K / 32;
    constexpr int CPR = K / 8;                  // 16B chunks per row
    constexpr int LOG_CPR = (K == 256) ? 5 : 4;
    constexpr int RPI = 64 / CPR;               // rows per staging issue
    constexpr int ISSUES = 16 / RPI;            // per wave (16 rows/wave)
    const int N = 2 * Nh;
    __shared__ bf16 A_s[64 * K];

    const int z = blockIdx.z;
    const bool isKV = (int)blockIdx.x < nbKV;
    const int bx = isKV ? blockIdx.x : blockIdx.x - nbKV;
    const int M = isKV ? Mkv : Mqs;
    const bf16* Bt = (isKV ? BtKV : BtQS) + (size_t)z * N * K;
    const float* b1 = (isKV ? bk : bq) + (size_t)z * Nh;
    const float* b2 = (isKV ? bv : bs) + (size_t)z * Nh;

    const int lane = threadIdx.x & 63;
    const int w = threadIdx.x >> 6;             // 0..3 (col group)
    const int lm = lane & 15;
    const int q = lane >> 4;
    const int mbase = bx * 64;
    const int n0 = blockIdx.y * 256;

    // ---- stage A tile (64 x K bf16), XOR chunk swizzle c^(row&7) ----
    if constexpr (GATHER) {
        // fp32 gather path (K must be 256): thread t -> row t>>2, 64-col quarter t&3
        const float* F = (const float*)Asrc;
        const int* ip = idx + (size_t)z * idxStr;
        int row = threadIdx.x >> 2;
        int qq = threadIdx.x & 3;
        int grow = mbase + row; if (grow >= M) grow = M - 1;
        const float* srcp = F + (size_t)ip[grow] * K + qq * 64;
        bf16* dst = A_s + (size_t)row * K;
        #pragma unroll
        for (int c0 = 0; c0 < 2; c0++) {
            float4 f[4][2];
            #pragma unroll
            for (int c = 0; c < 4; c++) {
                f[c][0] = *(const float4*)(srcp + (c0 * 4 + c) * 8);
                f[c][1] = *(const float4*)(srcp + (c0 * 4 + c) * 8 + 4);
            }
            #pragma unroll
            for (int c = 0; c < 4; c++) {
                int gch = qq * 8 + c0 * 4 + c;
                int lp = gch ^ (row & 7);
                bf16 tmp[8] = {(bf16)f[c][0].x, (bf16)f[c][0].y, (bf16)f[c][0].z, (bf16)f[c][0].w,
                               (bf16)f[c][1].x, (bf16)f[c][1].y, (bf16)f[c][1].z, (bf16)f[c][1].w};
                *(short8*)(dst + lp * 8) = *(const short8*)tmp;
            }
        }
    } else {
        const bf16* A = (const bf16*)Asrc + (size_t)z * Astr;
        const int ch = lane & (CPR - 1);
        const int rsub = lane >> LOG_CPR;
        #pragma unroll
        for (int i = 0; i < ISSUES; i++) {
            int row = w * 16 + i * RPI + rsub;
            int grow = mbase + row; grow = grow < M ? grow : M - 1;
            int gch = ch ^ (row & 7);
            load_lds16(A + (size_t)grow * K + gch * 8,
                       A_s + (size_t)(w * 16 + i * RPI) * K);
        }
    }

    const bf16* bp[4];
    #pragma unroll
    for (int ni = 0; ni < 4; ni++)
        bp[ni] = Bt + (size_t)(n0 + w * 64 + ni * 16 + lm) * K + q * 8;

    floatx4 acc[4][4];
    #pragma unroll
    for (int i = 0; i < 4; i++)
        #pragma unroll
        for (int j = 0; j < 4; j++)
            acc[i][j] = (floatx4){0.f, 0.f, 0.f, 0.f};

    __syncthreads();

    short8 bn[4];
    #pragma unroll
    for (int ni = 0; ni < 4; ni++) bn[ni] = *(const short8*)(bp[ni]);

    #pragma unroll
    for (int kc = 0; kc < KC; kc++) {
        short8 bc[4];
        #pragma unroll
        for (int ni = 0; ni < 4; ni++) bc[ni] = bn[ni];
        if (kc + 1 < KC) {
            #pragma unroll
            for (int ni = 0; ni < 4; ni++)
                bn[ni] = *(const short8*)(bp[ni] + (kc + 1) * 32);
        }
        short8 af[4];
        #pragma unroll
        for (int mi = 0; mi < 4; mi++) {
            int row = mi * 16 + lm;
            af[mi] = *(const short8*)(A_s + row * K + (((kc * 4 + q) ^ (lm & 7)) * 8));
        }
        #pragma unroll
        for (int mi = 0; mi < 4; mi++)
            #pragma unroll
            for (int ni = 0; ni < 4; ni++)
                acc[mi][ni] = __builtin_amdgcn_mfma_f32_16x16x32_bf16(
                    af[mi], bc[ni], acc[mi][ni], 0, 0, 0);
    }

    // C/D layout: col = lane&15, row = (lane>>4)*4 + reg  [m89]
    if (isKV) {
        bf16* C = Ckv + (size_t)z * CkvStr;
        __syncthreads();                        // A_s dead; reuse as transpose stage
        bf16* stg = A_s + (size_t)w * (16 * 72);
        #pragma unroll
        for (int p = 0; p < 4; p++) {           // p == mi
            #pragma unroll
            for (int ni = 0; ni < 4; ni++) {
                int colg = n0 + w * 64 + ni * 16 + lm;
                float bias = (colg < Nh) ? b1[colg] : b2[colg - Nh];
                #pragma unroll
                for (int rg = 0; rg < 4; rg++)
                    stg[(q * 4 + rg) * 72 + ni * 16 + lm] = (bf16)(acc[p][ni][rg] + bias);
            }
            #pragma unroll
            for (int it = 0; it < 2; it++) {
                int rl = it * 8 + (lane >> 3);
                int grow = mbase + p * 16 + rl;
                short8 vv = *(const short8*)(stg + rl * 72 + (lane & 7) * 8);
                if (grow < M)
                    *(short8*)(C + (size_t)grow * N + n0 + w * 64 + (lane & 7) * 8) = vv;
            }
        }
    } else {
        float* C = Cqs + (size_t)z * CqsStr;
        #pragma unroll
        for (int ni = 0; ni < 4; ni++) {
            int colg = n0 + w * 64 + ni * 16 + lm;
            float bias = (colg < Nh) ? b1[colg] : b2[colg - Nh];
            #pragma unroll
            for (int mi = 0; mi < 4; mi++) {
                int rb = mbase + mi * 16 + q * 4;
                #pragma unroll
                for (int rg = 0; rg < 4; rg++) {
                    int rr = rb + rg;
                    if (rr < M) C[(size_t)rr * N + colg] = acc[mi][ni][rg] + bias;
                }
            }
        }
    }
}

// ---------------- all weight packs in ONE dispatch (job via blockIdx.z) ----------
__global__ __launch_bounds__(256) void pack_all(
    const float* __restrict__ l1_Wk, const float* __restrict__ l1_Wv,
    const float* __restrict__ l1_Wq, const float* __restrict__ l1_Ws,
    const float* __restrict__ l2_Wk, const float* __restrict__ l2_Wv,
    const float* __restrict__ l2_Wq, const float* __restrict__ l2_Ws,
    const float* __restrict__ l3_Wk, const float* __restrict__ l3_Wv,
    const float* __restrict__ l3_Wq, const float* __restrict__ l3_Ws,
    bf16* __restrict__ Wkv1, bf16* __restrict__ Wqs1,
    bf16* __restrict__ Wkv2, bf16* __restrict__ Wqs2,
    bf16* __restrict__ Wkv3, bf16* __restrict__ Wqs3)
{
    int job = blockIdx.z, r = blockIdx.y, nn = blockIdx.x, k = threadIdx.x;
    const float *W1, *W2; bf16* Wt; int K, Nh;
    switch (job) {
        case 0: W1 = l1_Wk; W2 = l1_Wv; Wt = Wkv1; K = 256; Nh = 256; break;
        case 1: W1 = l1_Wq; W2 = l1_Ws; Wt = Wqs1; K = 256; Nh = 256; break;
        case 2: W1 = l2_Wk; W2 = l2_Wv; Wt = Wkv2; K = 256; Nh = 128; break;
        case 3: W1 = l2_Wq; W2 = l2_Ws; Wt = Wqs2; K = 256; Nh = 128; break;
        case 4: W1 = l3_Wk; W2 = l3_Wv; Wt = Wkv3; K = 128; Nh = 256; break;
        default: W1 = l3_Wq; W2 = l3_Ws; Wt = Wqs3; K = 128; Nh = 256; break;
    }
    if (nn >= 2 * Nh || k >= K) return;
    size_t wstride = (size_t)K * Nh;
    float v = (nn < Nh) ? W1[(size_t)r * wstride + (size_t)k * Nh + nn]
                        : W2[(size_t)r * wstride + (size_t)k * Nh + (nn - Nh)];
    Wt[(size_t)r * 2 * wstride + (size_t)nn * K + k] = (bf16)v;
}

// ---------------- fused attention + gated skip ----------------
// Lane-contiguous channel map: c = lane*CPL + j. Head h owns lanes
// [h*LPH,(h+1)*LPH); per-head dot = sub-wave xor-reduction.
// qs row = [q(hc)|s(hc)] fp32; kv row = [k(hc)|v(hc)] bf16.
template<int CPL, int HEADS>   // hc = CPL*64
__global__ __launch_bounds__(256) void attn_gate(
    const float* __restrict__ qs, size_t qsStr,
    const bf16* __restrict__ kv, size_t kvStr,
    const int* __restrict__ src,
    const float* __restrict__ Wb,
    float* __restrict__ yf, size_t yfStr,
    bf16* __restrict__ yb, size_t ybStr,
    int ndst, float scale)
{
    constexpr int hc = CPL * 64;
    constexpr int LPH = 64 / HEADS;
    const int z = blockIdx.y;
    int lane = threadIdx.x & 63;
    int d = blockIdx.x * 4 + (threadIdx.x >> 6);
    if (d >= ndst) return;
    qs += (size_t)z * qsStr;
    kv += (size_t)z * kvStr;
    src += (size_t)z * ndst * FAN;
    Wb += (size_t)z * 3 * hc;

    const float* qp = qs + (size_t)d * (2 * hc) + lane * CPL;
    float qv[CPL], xv[CPL];
    if constexpr (CPL == 2) {
        float2 a = *(const float2*)qp;
        float2 b = *(const float2*)(qp + hc);
        qv[0] = a.x; qv[1] = a.y; xv[0] = b.x; xv[1] = b.y;
    } else {
        float4 a = *(const float4*)qp;
        float4 b = *(const float4*)(qp + hc);
        qv[0] = a.x; qv[1] = a.y; qv[2] = a.z; qv[3] = a.w;
        xv[0] = b.x; xv[1] = b.y; xv[2] = b.z; xv[3] = b.w;
    }
    const int* sp = src + (size_t)d * FAN;
    int sidx[FAN];
    #pragma unroll
    for (int e = 0; e < FAN; e++) sidx[e] = sp[e];

    float part[FAN];
    #pragma unroll
    for (int e = 0; e < FAN; e++) {
        const bf16* kp = kv + (size_t)sidx[e] * (2 * hc) + lane * CPL;
        if constexpr (CPL == 2) {
            float2 kf = cvt_bf2(*(const unsigned*)kp);
            part[e] = qv[0] * kf.x + qv[1] * kf.y;
        } else {
            uint2 u = *(const uint2*)kp;
            float2 k0 = cvt_bf2(u.x), k1 = cvt_bf2(u.y);
            part[e] = qv[0] * k0.x + qv[1] * k0.y + qv[2] * k1.x + qv[3] * k1.y;
        }
    }
    float logit[FAN], mx = -1e30f;
    #pragma unroll
    for (int e = 0; e < FAN; e++) {
        float dt = part[e];
        #pragma unroll
        for (int off = LPH / 2; off > 0; off >>= 1) dt += __shfl_xor(dt, off, 64);
        dt *= scale;
        logit[e] = dt;
        mx = fmaxf(mx, dt);
    }
    float zsum = 0.f, p[FAN];
    #pragma unroll
    for (int e = 0; e < FAN; e++) { p[e] = __expf(logit[e] - mx); zsum += p[e]; }
    float inv = 1.f / zsum;

    float ov[CPL];
    #pragma unroll
    for (int j = 0; j < CPL; j++) ov[j] = 0.f;
    #pragma unroll
    for (int e = 0; e < FAN; e++) {
        const bf16* vp = kv + (size_t)sidx[e] * (2 * hc) + hc + lane * CPL;
        if constexpr (CPL == 2) {
            float2 vf = cvt_bf2(*(const unsigned*)vp);
            ov[0] += p[e] * vf.x; ov[1] += p[e] * vf.y;
        } else {
            uint2 u = *(const uint2*)vp;
            float2 v0 = cvt_bf2(u.x), v1 = cvt_bf2(u.y);
            ov[0] += p[e] * v0.x; ov[1] += p[e] * v0.y;
            ov[2] += p[e] * v1.x; ov[3] += p[e] * v1.y;
        }
    }
    #pragma unroll
    for (int j = 0; j < CPL; j++) ov[j] *= inv;

    float s = 0.f;
    #pragma unroll
    for (int j = 0; j < CPL; j++) {
        int c = lane * CPL + j;
        s += ov[j] * Wb[c] + xv[j] * Wb[hc + c] + (ov[j] - xv[j]) * Wb[2 * hc + c];
    }
    #pragma unroll
    for (int off = 32; off > 0; off >>= 1) s += __shfl_xor(s, off, 64);
    float g = 1.f / (1.f + __expf(-s));

    float yv[CPL];
    #pragma unroll
    for (int j = 0; j < CPL; j++) yv[j] = g * xv[j] + (1.f - g) * ov[j];

    if (yf) {
        float* op = yf + (size_t)z * yfStr + (size_t)d * hc + lane * CPL;
        if constexpr (CPL == 2) *(float2*)op = make_float2(yv[0], yv[1]);
        else *(float4*)op = make_float4(yv[0], yv[1], yv[2], yv[3]);
    }
    if (yb) {
        bf16* op = yb + (size_t)z * ybStr + (size_t)d * hc + lane * CPL;
        bf16 tmp[CPL];
        #pragma unroll
        for (int j = 0; j < CPL; j++) tmp[j] = (bf16)yv[j];
        if constexpr (CPL == 2) *(short2v*)op = *(const short2v*)tmp;
        else *(short4v*)op = *(const short4v*)tmp;
    }
}

// ---------------- column stats (bf16 input), relation via blockIdx.y ----------------
__global__ __launch_bounds__(256) void colstat_partial(
    const bf16* __restrict__ x, size_t xStr, int M,
    float* __restrict__ ps, float* __restrict__ pss)
{
    int z = blockIdx.y;
    const bf16* xp = x + (size_t)z * xStr;
    int f = threadIdx.x;
    int b = blockIdx.x;   // 64
    float s = 0.f, ss = 0.f;
    for (int r = b; r < M; r += 64) {
        float v = (float)xp[(size_t)r * H + f];
        s += v; ss += v * v;
    }
    ps[((size_t)z * 64 + b) * H + f] = s;
    pss[((size_t)z * 64 + b) * H + f] = ss;
}

__global__ __launch_bounds__(256) void colfinal_norm_elu(
    const float* __restrict__ ps, const float* __restrict__ pss,
    bf16* __restrict__ x, size_t xStr, int M)
{
    int z = blockIdx.y;
    bf16* xp = x + (size_t)z * xStr;
    int c = threadIdx.x;
    float s = 0.f, ss = 0.f;
    #pragma unroll 8
    for (int b = 0; b < 64; b++) {
        s += ps[((size_t)z * 64 + b) * H + c];
        ss += pss[((size_t)z * 64 + b) * H + c];
    }
    float mu = s / M;
    float istd = rsqrtf(ss / M - mu * mu + 1e-5f);
    for (int r = blockIdx.x; r < M; r += gridDim.x) {
        float t = ((float)xp[(size_t)r * H + c] - mu) * istd;
        xp[(size_t)r * H + c] = (bf16)(t > 0.f ? t : __expf(t) - 1.0f);
    }
}

// ---------------- semantic attention across the 3 relations ----------------
__global__ __launch_bounds__(256) void semantic_kernel(
    const float* __restrict__ emb,   // (3, N3, H)
    const float* __restrict__ Wo, const float* __restrict__ bo,
    const float* __restrict__ uo, const float* __restrict__ rl,
    float* __restrict__ outp)
{
    __shared__ float m_s[3][H];
    __shared__ float red[H];
    __shared__ float score_s[3];
    int n = blockIdx.x, c = threadIdx.x;
    for (int r = 0; r < 3; r++)
        m_s[r][c] = emb[((size_t)r * N3 + n) * H + c] * rl[r];
    __syncthreads();
    for (int r = 0; r < 3; r++) {
        float t = bo[c];
        for (int k2 = 0; k2 < H; k2++) t += m_s[r][k2] * Wo[k2 * H + c];
        red[c] = tanhf(t) * uo[c];
        __syncthreads();
        for (int s = 128; s > 0; s >>= 1) {
            if (c < s) red[c] += red[c + s];
            __syncthreads();
        }
        if (c == 0) score_s[r] = red[0];
        __syncthreads();
    }
    float s0 = score_s[0], s1 = score_s[1], s2 = score_s[2];
    float mx = fmaxf(s0, fmaxf(s1, s2));
    float e0 = __expf(s0 - mx), e1 = __expf(s1 - mx), e2 = __expf(s2 - mx);
    float zi = 1.0f / (e0 + e1 + e2);
    outp[(size_t)n * H + c] = (m_s[0][c] * e0 + m_s[1][c] * e1 + m_s[2][c] * e2) * zi;
}

extern "C" void kernel_launch(void* const* d_in, const int* in_sizes, int n_in,
                              void* d_out, int out_size, void* d_ws, size_t ws_size,
                              hipStream_t stream) {
    const float* features = (const float*)d_in[0];
    const int*   n_ids    = (const int*)d_in[1];
    const int*   src1     = (const int*)d_in[2];
    const int*   src2     = (const int*)d_in[4];
    const int*   src3     = (const int*)d_in[6];
    const float* l1_Wq = (const float*)d_in[8];
    const float* l1_Wk = (const float*)d_in[9];
    const float* l1_Wv = (const float*)d_in[10];
    const float* l1_Ws = (const float*)d_in[11];
    const float* l1_bq = (const float*)d_in[12];
    const float* l1_bk = (const float*)d_in[13];
    const float* l1_bv = (const float*)d_in[14];
    const float* l1_bs = (const float*)d_in[15];
    const float* l1_Wb = (const float*)d_in[16];
    const float* l2_Wq = (const float*)d_in[17];
    const float* l2_Wk = (const float*)d_in[18];
    const float* l2_Wv = (const float*)d_in[19];
    const float* l2_Ws = (const float*)d_in[20];
    const float* l2_bq = (const float*)d_in[21];
    const float* l2_bk = (const float*)d_in[22];
    const float* l2_bv = (const float*)d_in[23];
    const float* l2_bs = (const float*)d_in[24];
    const float* l2_Wb = (const float*)d_in[25];
    const float* l3_Wq = (const float*)d_in[26];
    const float* l3_Wk = (const float*)d_in[27];
    const float* l3_Wv = (const float*)d_in[28];
    const float* l3_Ws = (const float*)d_in[29];
    const float* l3_bq = (const float*)d_in[30];
    const float* l3_bk = (const float*)d_in[31];
    const float* l3_bv = (const float*)d_in[32];
    const float* l3_bs = (const float*)d_in[33];
    const float* l3_Wb = (const float*)d_in[34];
    const float* w_omega = (const float*)d_in[35];
    const float* b_omega = (const float*)d_in[36];
    const float* u_omega = (const float*)d_in[37];
    const float* rl      = (const float*)d_in[38];

    // ---- workspace layout: per-relation buffers ----
    float* ws = (float*)d_ws;
    size_t o = 0;
    float* emb = ws + o; o += (size_t)3 * N3 * H;
    float* qs1 = ws + o; o += (size_t)3 * N1 * 512;
    float* qs2 = ws + o; o += (size_t)3 * N2 * 256;
    float* qs3 = ws + o; o += (size_t)3 * N3 * 512;
    float* ps  = ws + o; o += (size_t)3 * 64 * H;
    float* pss = ws + o; o += (size_t)3 * 64 * H;

    bf16* bws = (bf16*)(ws + o);
    size_t b = 0;
    bf16* kv1 = bws + b; b += (size_t)3 * N0 * 512;
    bf16* x1b = bws + b; b += (size_t)3 * N1 * 256;
    bf16* kv2 = bws + b; b += (size_t)3 * N1 * 256;
    bf16* x2b = bws + b; b += (size_t)3 * N2 * 128;
    bf16* kv3 = bws + b; b += (size_t)3 * N2 * 512;
    bf16* Wkv1 = bws + b; b += (size_t)3 * 512 * H;
    bf16* Wqs1 = bws + b; b += (size_t)3 * 512 * H;
    bf16* Wkv2 = bws + b; b += (size_t)3 * 256 * H;
    bf16* Wqs2 = bws + b; b += (size_t)3 * 256 * H;
    bf16* Wkv3 = bws + b; b += (size_t)3 * 512 * 128;
    bf16* Wqs3 = bws + b; b += (size_t)3 * 512 * 128;

    const float sc128 = 0.088388347648318447f;  // 1/sqrt(128)
    const float sc256 = 0.0625f;                // 1/sqrt(256)

    // ---- all weight packs, one dispatch ----
    pack_all<<<dim3(512, 3, 6), 256, 0, stream>>>(
        l1_Wk, l1_Wv, l1_Wq, l1_Ws, l2_Wk, l2_Wv, l2_Wq, l2_Ws,
        l3_Wk, l3_Wv, l3_Wq, l3_Ws, Wkv1, Wqs1, Wkv2, Wqs2, Wkv3, Wqs3);

    // ---- L1: fused gather-GEMM. din=256, heads=2, hc=256, N=512, K=256 ----
    {
        int nbKV = (N0 + 63) / 64, nbQS = (N1 + 63) / 64;
        gemm_dual<256, true><<<dim3(nbKV + nbQS, 2, 3), 256, 0, stream>>>(
            features, 0, n_ids, (size_t)N0, Wkv1, Wqs1, l1_bk, l1_bv, l1_bq, l1_bs, 256,
            kv1, (size_t)N0 * 512, N0, qs1, (size_t)N1 * 512, N1, nbKV);
    }
    attn_gate<4, 2><<<dim3((N1 + 3) / 4, 3), 256, 0, stream>>>(
        qs1, (size_t)N1 * 512, kv1, (size_t)N0 * 512, src1, l1_Wb,
        (float*)nullptr, 0, x1b, (size_t)N1 * 256, N1, sc128);
    colstat_partial<<<dim3(64, 3), 256, 0, stream>>>(x1b, (size_t)N1 * 256, N1, ps, pss);
    colfinal_norm_elu<<<dim3(128, 3), 256, 0, stream>>>(ps, pss, x1b, (size_t)N1 * 256, N1);

    // ---- L2: din=256, heads=1, hc=128, N=256, K=256 ----
    {
        int nbKV = (N1 + 63) / 64, nbQS = (N2 + 63) / 64;
        gemm_dual<256, false><<<dim3(nbKV + nbQS, 1, 3), 256, 0, stream>>>(
            x1b, (size_t)N1 * 256, nullptr, 0, Wkv2, Wqs2, l2_bk, l2_bv, l2_bq, l2_bs, 128,
            kv2, (size_t)N1 * 256, N1, qs2, (size_t)N2 * 256, N2, nbKV);
    }
    attn_gate<2, 1><<<dim3((N2 + 3) / 4, 3), 256, 0, stream>>>(
        qs2, (size_t)N2 * 256, kv2, (size_t)N1 * 256, src2, l2_Wb,
        (float*)nullptr, 0, x2b, (size_t)N2 * 128, N2, sc128);

    // ---- L3: din=128, heads=1, hc=256, N=512, K=128 ----
    {
        int nbKV = (N2 + 63) / 64, nbQS = (N3 + 63) / 64;
        gemm_dual<128, false><<<dim3(nbKV + nbQS, 2, 3), 256, 0, stream>>>(
            x2b, (size_t)N2 * 128, nullptr, 0, Wkv3, Wqs3, l3_bk, l3_bv, l3_bq, l3_bs, 256,
            kv3, (size_t)N2 * 512, N2, qs3, (size_t)N3 * 512, N3, nbKV);
    }
    attn_gate<4, 1><<<dim3((N3 + 3) / 4, 3), 256, 0, stream>>>(
        qs3, (size_t)N3 * 512, kv3, (size_t)N2 * 512, src3, l3_Wb,
        emb, (size_t)N3 * H, (bf16*)nullptr, 0, N3, sc256);

    semantic_kernel<<<N3, 256, 0, stream>>>(emb, w_omega, b_omega, u_omega, rl, (float*)d_out);
}

// Round 8
// 631.661 us; speedup vs baseline: 1.0189x; 1.0189x over previous
//
#include <hip/hip_runtime.h>
#include <hip/hip_bf16.h>
#include <math.h>

#define H 256
#define N0 50000
#define N1 10000
#define N2 4000
#define N3 1024
#define FAN 16

typedef __hip_bfloat16 bf16;
typedef __attribute__((ext_vector_type(8))) short short8;
typedef __attribute__((ext_vector_type(4))) short short4v;
typedef __attribute__((ext_vector_type(2))) short short2v;
typedef __attribute__((ext_vector_type(4))) float floatx4;

typedef const __attribute__((address_space(1))) void* gas_ptr;
typedef __attribute__((address_space(3))) void* las_ptr;

__device__ __forceinline__ void load_lds16(const void* g, void* l) {
    __builtin_amdgcn_global_load_lds((gas_ptr)g, (las_ptr)l, 16, 0, 0);
}

__device__ __forceinline__ float2 cvt_bf2(unsigned u) {
    union { unsigned q; float f; } lo, hi;
    lo.q = u << 16; hi.q = u & 0xffff0000u;
    return make_float2(lo.f, hi.f);
}

// ---------------- dual-output LDS-A MFMA GEMM ----------------
// One dispatch computes BOTH the kv GEMM (bf16 out) and qs GEMM (fp32 out):
// grid.x < nbKV -> kv blocks, else qs blocks. Tile 64 rows x (64*NW) cols,
// NW waves (wave w owns col group w). A-tile (64xK bf16) staged ONCE via
// global_load_lds (16B, XOR chunk swizzle c^(row&7)) -> one barrier, then a
// barrier-free K-loop; B from L2-resident global with one-step reg prefetch.
// NW=8: one block covers all 512 cols -> A staged once per row-tile (2x the
// MFMA per staged byte vs NW=4/grid.y=2).
template<int K, int NW>
__global__ __launch_bounds__(64 * NW, NW == 8 ? 4 : 5) void gemm_dual(
    const bf16* __restrict__ A, size_t Astr,
    const bf16* __restrict__ BtKV, const bf16* __restrict__ BtQS,
    const float* __restrict__ bk, const float* __restrict__ bv,
    const float* __restrict__ bq, const float* __restrict__ bs, int Nh,
    bf16* __restrict__ Ckv, size_t CkvStr, int Mkv,
    float* __restrict__ Cqs, size_t CqsStr, int Mqs,
    int nbKV)
{
    constexpr int KC = K / 32;                  // mfma k-steps
    constexpr int CPR = K / 8;                  // 16B chunks per A row
    constexpr int RPI = 64 / CPR;               // rows per wave staging issue
    constexpr int ISS = 64 / (NW * RPI);        // staging issues per wave
    const int N = 2 * Nh;
    __shared__ bf16 A_s[64 * K];

    const int z = blockIdx.z;
    const bool isKV = (int)blockIdx.x < nbKV;
    const int bx = isKV ? blockIdx.x : blockIdx.x - nbKV;
    const int M = isKV ? Mkv : Mqs;
    const bf16* Bt = (isKV ? BtKV : BtQS) + (size_t)z * N * K;
    const float* b1 = (isKV ? bk : bq) + (size_t)z * Nh;
    const float* b2 = (isKV ? bv : bs) + (size_t)z * Nh;
    A += (size_t)z * Astr;

    const int lane = threadIdx.x & 63;
    const int w = threadIdx.x >> 6;             // 0..NW-1 (col group)
    const int lm = lane & 15;
    const int q = lane >> 4;
    const int mbase = bx * 64;
    const int n0 = blockIdx.y * (64 * NW);

    // ---- stage A tile (64 x K): LDS row r holds chunks permuted by c^(r&7) ----
    {
        const int ch = lane & (CPR - 1);
        const int rsub = lane / CPR;
        #pragma unroll
        for (int i = 0; i < ISS; i++) {
            int rbase = (i * NW + w) * RPI;
            int row = rbase + rsub;
            int grow = mbase + row; grow = grow < M ? grow : M - 1;
            int gch = ch ^ (row & 7);
            load_lds16(A + (size_t)grow * K + gch * 8, A_s + (size_t)rbase * K);
        }
    }

    const bf16* bp[4];
    #pragma unroll
    for (int ni = 0; ni < 4; ni++)
        bp[ni] = Bt + (size_t)(n0 + w * 64 + ni * 16 + lm) * K + q * 8;

    floatx4 acc[4][4];
    #pragma unroll
    for (int i = 0; i < 4; i++)
        #pragma unroll
        for (int j = 0; j < 4; j++)
            acc[i][j] = (floatx4){0.f, 0.f, 0.f, 0.f};

    __syncthreads();

    short8 bn[4];
    #pragma unroll
    for (int ni = 0; ni < 4; ni++) bn[ni] = *(const short8*)(bp[ni]);

    #pragma unroll
    for (int kc = 0; kc < KC; kc++) {
        short8 bc[4];
        #pragma unroll
        for (int ni = 0; ni < 4; ni++) bc[ni] = bn[ni];
        if (kc + 1 < KC) {
            #pragma unroll
            for (int ni = 0; ni < 4; ni++)
                bn[ni] = *(const short8*)(bp[ni] + (kc + 1) * 32);
        }
        short8 af[4];
        #pragma unroll
        for (int mi = 0; mi < 4; mi++) {
            int row = mi * 16 + lm;
            af[mi] = *(const short8*)(A_s + row * K + (((kc * 4 + q) ^ (lm & 7)) * 8));
        }
        #pragma unroll
        for (int mi = 0; mi < 4; mi++)
            #pragma unroll
            for (int ni = 0; ni < 4; ni++)
                acc[mi][ni] = __builtin_amdgcn_mfma_f32_16x16x32_bf16(
                    af[mi], bc[ni], acc[mi][ni], 0, 0, 0);
    }

    // C/D layout: col = lane&15, row = (lane>>4)*4 + reg  [m89]
    if (isKV) {
        bf16* C = Ckv + (size_t)z * CkvStr;
        __syncthreads();                        // A_s dead; reuse as transpose stage
        bf16* stg = A_s + (size_t)w * (16 * 72);
        #pragma unroll
        for (int p = 0; p < 4; p++) {           // p == mi
            #pragma unroll
            for (int ni = 0; ni < 4; ni++) {
                int colg = n0 + w * 64 + ni * 16 + lm;
                float bias = (colg < Nh) ? b1[colg] : b2[colg - Nh];
                #pragma unroll
                for (int rg = 0; rg < 4; rg++)
                    stg[(q * 4 + rg) * 72 + ni * 16 + lm] = (bf16)(acc[p][ni][rg] + bias);
            }
            #pragma unroll
            for (int it = 0; it < 2; it++) {
                int rl = it * 8 + (lane >> 3);
                int grow = mbase + p * 16 + rl;
                short8 vv = *(const short8*)(stg + rl * 72 + (lane & 7) * 8);
                if (grow < M)
                    *(short8*)(C + (size_t)grow * N + n0 + w * 64 + (lane & 7) * 8) = vv;
            }
        }
    } else {
        float* C = Cqs + (size_t)z * CqsStr;
        #pragma unroll
        for (int ni = 0; ni < 4; ni++) {
            int colg = n0 + w * 64 + ni * 16 + lm;
            float bias = (colg < Nh) ? b1[colg] : b2[colg - Nh];
            #pragma unroll
            for (int mi = 0; mi < 4; mi++) {
                int rb = mbase + mi * 16 + q * 4;
                #pragma unroll
                for (int rg = 0; rg < 4; rg++) {
                    int rr = rb + rg;
                    if (rr < M) C[(size_t)rr * N + colg] = acc[mi][ni][rg] + bias;
                }
            }
        }
    }
}

// ---------------- gather rows of features -> bf16, relation via blockIdx.y ----------
// 32 lanes-groups of 8 cols: float4 x2 in, short8 (16B) out per thread.
__global__ __launch_bounds__(256) void gather_bf16(
    const float* __restrict__ F, const int* __restrict__ n_ids, bf16* __restrict__ out,
    int nrows)
{
    int z = blockIdx.y;
    const int* idx = n_ids + (size_t)z * nrows;
    bf16* o = out + (size_t)z * nrows * H;
    int t = blockIdx.x * 256 + threadIdx.x;
    int row = t >> 5;                 // 32 threads per row
    if (row >= nrows) return;
    int c8 = (t & 31) * 8;
    const float* src = F + (size_t)idx[row] * H + c8;
    float4 a = *(const float4*)src;
    float4 b = *(const float4*)(src + 4);
    bf16 tmp[8] = {(bf16)a.x, (bf16)a.y, (bf16)a.z, (bf16)a.w,
                   (bf16)b.x, (bf16)b.y, (bf16)b.z, (bf16)b.w};
    *(short8*)(o + (size_t)row * H + c8) = *(const short8*)tmp;
}

// ---------------- all weight packs in ONE dispatch (job via blockIdx.z) ----------
__global__ __launch_bounds__(256) void pack_all(
    const float* __restrict__ l1_Wk, const float* __restrict__ l1_Wv,
    const float* __restrict__ l1_Wq, const float* __restrict__ l1_Ws,
    const float* __restrict__ l2_Wk, const float* __restrict__ l2_Wv,
    const float* __restrict__ l2_Wq, const float* __restrict__ l2_Ws,
    const float* __restrict__ l3_Wk, const float* __restrict__ l3_Wv,
    const float* __restrict__ l3_Wq, const float* __restrict__ l3_Ws,
    bf16* __restrict__ Wkv1, bf16* __restrict__ Wqs1,
    bf16* __restrict__ Wkv2, bf16* __restrict__ Wqs2,
    bf16* __restrict__ Wkv3, bf16* __restrict__ Wqs3)
{
    int job = blockIdx.z, r = blockIdx.y, nn = blockIdx.x, k = threadIdx.x;
    const float *W1, *W2; bf16* Wt; int K, Nh;
    switch (job) {
        case 0: W1 = l1_Wk; W2 = l1_Wv; Wt = Wkv1; K = 256; Nh = 256; break;
        case 1: W1 = l1_Wq; W2 = l1_Ws; Wt = Wqs1; K = 256; Nh = 256; break;
        case 2: W1 = l2_Wk; W2 = l2_Wv; Wt = Wkv2; K = 256; Nh = 128; break;
        case 3: W1 = l2_Wq; W2 = l2_Ws; Wt = Wqs2; K = 256; Nh = 128; break;
        case 4: W1 = l3_Wk; W2 = l3_Wv; Wt = Wkv3; K = 128; Nh = 256; break;
        default: W1 = l3_Wq; W2 = l3_Ws; Wt = Wqs3; K = 128; Nh = 256; break;
    }
    if (nn >= 2 * Nh || k >= K) return;
    size_t wstride = (size_t)K * Nh;
    float v = (nn < Nh) ? W1[(size_t)r * wstride + (size_t)k * Nh + nn]
                        : W2[(size_t)r * wstride + (size_t)k * Nh + (nn - Nh)];
    Wt[(size_t)r * 2 * wstride + (size_t)nn * K + k] = (bf16)v;
}

// ---------------- fused attention + gated skip ----------------
// Lane-contiguous channel map: c = lane*CPL + j. Head h owns lanes
// [h*LPH,(h+1)*LPH); per-head dot = sub-wave xor-reduction.
// qs row = [q(hc)|s(hc)] fp32; kv row = [k(hc)|v(hc)] bf16.
template<int CPL, int HEADS>   // hc = CPL*64
__global__ __launch_bounds__(256) void attn_gate(
    const float* __restrict__ qs, size_t qsStr,
    const bf16* __restrict__ kv, size_t kvStr,
    const int* __restrict__ src,
    const float* __restrict__ Wb,
    float* __restrict__ yf, size_t yfStr,
    bf16* __restrict__ yb, size_t ybStr,
    int ndst, float scale)
{
    constexpr int hc = CPL * 64;
    constexpr int LPH = 64 / HEADS;
    const int z = blockIdx.y;
    int lane = threadIdx.x & 63;
    int d = blockIdx.x * 4 + (threadIdx.x >> 6);
    if (d >= ndst) return;
    qs += (size_t)z * qsStr;
    kv += (size_t)z * kvStr;
    src += (size_t)z * ndst * FAN;
    Wb += (size_t)z * 3 * hc;

    const float* qp = qs + (size_t)d * (2 * hc) + lane * CPL;
    float qv[CPL], xv[CPL];
    if constexpr (CPL == 2) {
        float2 a = *(const float2*)qp;
        float2 b = *(const float2*)(qp + hc);
        qv[0] = a.x; qv[1] = a.y; xv[0] = b.x; xv[1] = b.y;
    } else {
        float4 a = *(const float4*)qp;
        float4 b = *(const float4*)(qp + hc);
        qv[0] = a.x; qv[1] = a.y; qv[2] = a.z; qv[3] = a.w;
        xv[0] = b.x; xv[1] = b.y; xv[2] = b.z; xv[3] = b.w;
    }
    const int* sp = src + (size_t)d * FAN;
    int sidx[FAN];
    #pragma unroll
    for (int e = 0; e < FAN; e++) sidx[e] = sp[e];

    float part[FAN];
    #pragma unroll
    for (int e = 0; e < FAN; e++) {
        const bf16* kp = kv + (size_t)sidx[e] * (2 * hc) + lane * CPL;
        if constexpr (CPL == 2) {
            float2 kf = cvt_bf2(*(const unsigned*)kp);
            part[e] = qv[0] * kf.x + qv[1] * kf.y;
        } else {
            uint2 u = *(const uint2*)kp;
            float2 k0 = cvt_bf2(u.x), k1 = cvt_bf2(u.y);
            part[e] = qv[0] * k0.x + qv[1] * k0.y + qv[2] * k1.x + qv[3] * k1.y;
        }
    }
    float logit[FAN], mx = -1e30f;
    #pragma unroll
    for (int e = 0; e < FAN; e++) {
        float dt = part[e];
        #pragma unroll
        for (int off = LPH / 2; off > 0; off >>= 1) dt += __shfl_xor(dt, off, 64);
        dt *= scale;
        logit[e] = dt;
        mx = fmaxf(mx, dt);
    }
    float zsum = 0.f, p[FAN];
    #pragma unroll
    for (int e = 0; e < FAN; e++) { p[e] = __expf(logit[e] - mx); zsum += p[e]; }
    float inv = 1.f / zsum;

    float ov[CPL];
    #pragma unroll
    for (int j = 0; j < CPL; j++) ov[j] = 0.f;
    #pragma unroll
    for (int e = 0; e < FAN; e++) {
        const bf16* vp = kv + (size_t)sidx[e] * (2 * hc) + hc + lane * CPL;
        if constexpr (CPL == 2) {
            float2 vf = cvt_bf2(*(const unsigned*)vp);
            ov[0] += p[e] * vf.x; ov[1] += p[e] * vf.y;
        } else {
            uint2 u = *(const uint2*)vp;
            float2 v0 = cvt_bf2(u.x), v1 = cvt_bf2(u.y);
            ov[0] += p[e] * v0.x; ov[1] += p[e] * v0.y;
            ov[2] += p[e] * v1.x; ov[3] += p[e] * v1.y;
        }
    }
    #pragma unroll
    for (int j = 0; j < CPL; j++) ov[j] *= inv;

    float s = 0.f;
    #pragma unroll
    for (int j = 0; j < CPL; j++) {
        int c = lane * CPL + j;
        s += ov[j] * Wb[c] + xv[j] * Wb[hc + c] + (ov[j] - xv[j]) * Wb[2 * hc + c];
    }
    #pragma unroll
    for (int off = 32; off > 0; off >>= 1) s += __shfl_xor(s, off, 64);
    float g = 1.f / (1.f + __expf(-s));

    float yv[CPL];
    #pragma unroll
    for (int j = 0; j < CPL; j++) yv[j] = g * xv[j] + (1.f - g) * ov[j];

    if (yf) {
        float* op = yf + (size_t)z * yfStr + (size_t)d * hc + lane * CPL;
        if constexpr (CPL == 2) *(float2*)op = make_float2(yv[0], yv[1]);
        else *(float4*)op = make_float4(yv[0], yv[1], yv[2], yv[3]);
    }
    if (yb) {
        bf16* op = yb + (size_t)z * ybStr + (size_t)d * hc + lane * CPL;
        bf16 tmp[CPL];
        #pragma unroll
        for (int j = 0; j < CPL; j++) tmp[j] = (bf16)yv[j];
        if constexpr (CPL == 2) *(short2v*)op = *(const short2v*)tmp;
        else *(short4v*)op = *(const short4v*)tmp;
    }
}

// ---------------- column stats (bf16 input), relation via blockIdx.y ----------------
__global__ __launch_bounds__(256) void colstat_partial(
    const bf16* __restrict__ x, size_t xStr, int M,
    float* __restrict__ ps, float* __restrict__ pss)
{
    int z = blockIdx.y;
    const bf16* xp = x + (size_t)z * xStr;
    int f = threadIdx.x;
    int b = blockIdx.x;   // 64
    float s = 0.f, ss = 0.f;
    for (int r = b; r < M; r += 64) {
        float v = (float)xp[(size_t)r * H + f];
        s += v; ss += v * v;
    }
    ps[((size_t)z * 64 + b) * H + f] = s;
    pss[((size_t)z * 64 + b) * H + f] = ss;
}

__global__ __launch_bounds__(256) void colfinal_norm_elu(
    const float* __restrict__ ps, const float* __restrict__ pss,
    bf16* __restrict__ x, size_t xStr, int M)
{
    int z = blockIdx.y;
    bf16* xp = x + (size_t)z * xStr;
    int c = threadIdx.x;
    float s = 0.f, ss = 0.f;
    #pragma unroll 8
    for (int b = 0; b < 64; b++) {
        s += ps[((size_t)z * 64 + b) * H + c];
        ss += pss[((size_t)z * 64 + b) * H + c];
    }
    float mu = s / M;
    float istd = rsqrtf(ss / M - mu * mu + 1e-5f);
    for (int r = blockIdx.x; r < M; r += gridDim.x) {
        float t = ((float)xp[(size_t)r * H + c] - mu) * istd;
        xp[(size_t)r * H + c] = (bf16)(t > 0.f ? t : __expf(t) - 1.0f);
    }
}

// ---------------- semantic attention across the 3 relations ----------------
__global__ __launch_bounds__(256) void semantic_kernel(
    const float* __restrict__ emb,   // (3, N3, H)
    const float* __restrict__ Wo, const float* __restrict__ bo,
    const float* __restrict__ uo, const float* __restrict__ rl,
    float* __restrict__ outp)
{
    __shared__ float m_s[3][H];
    __shared__ float red[H];
    __shared__ float score_s[3];
    int n = blockIdx.x, c = threadIdx.x;
    for (int r = 0; r < 3; r++)
        m_s[r][c] = emb[((size_t)r * N3 + n) * H + c] * rl[r];
    __syncthreads();
    for (int r = 0; r < 3; r++) {
        float t = bo[c];
        for (int k2 = 0; k2 < H; k2++) t += m_s[r][k2] * Wo[k2 * H + c];
        red[c] = tanhf(t) * uo[c];
        __syncthreads();
        for (int s = 128; s > 0; s >>= 1) {
            if (c < s) red[c] += red[c + s];
            __syncthreads();
        }
        if (c == 0) score_s[r] = red[0];
        __syncthreads();
    }
    float s0 = score_s[0], s1 = score_s[1], s2 = score_s[2];
    float mx = fmaxf(s0, fmaxf(s1, s2));
    float e0 = __expf(s0 - mx), e1 = __expf(s1 - mx), e2 = __expf(s2 - mx);
    float zi = 1.0f / (e0 + e1 + e2);
    outp[(size_t)n * H + c] = (m_s[0][c] * e0 + m_s[1][c] * e1 + m_s[2][c] * e2) * zi;
}

extern "C" void kernel_launch(void* const* d_in, const int* in_sizes, int n_in,
                              void* d_out, int out_size, void* d_ws, size_t ws_size,
                              hipStream_t stream) {
    const float* features = (const float*)d_in[0];
    const int*   n_ids    = (const int*)d_in[1];
    const int*   src1     = (const int*)d_in[2];
    const int*   src2     = (const int*)d_in[4];
    const int*   src3     = (const int*)d_in[6];
    const float* l1_Wq = (const float*)d_in[8];
    const float* l1_Wk = (const float*)d_in[9];
    const float* l1_Wv = (const float*)d_in[10];
    const float* l1_Ws = (const float*)d_in[11];
    const float* l1_bq = (const float*)d_in[12];
    const float* l1_bk = (const float*)d_in[13];
    const float* l1_bv = (const float*)d_in[14];
    const float* l1_bs = (const float*)d_in[15];
    const float* l1_Wb = (const float*)d_in[16];
    const float* l2_Wq = (const float*)d_in[17];
    const float* l2_Wk = (const float*)d_in[18];
    const float* l2_Wv = (const float*)d_in[19];
    const float* l2_Ws = (const float*)d_in[20];
    const float* l2_bq = (const float*)d_in[21];
    const float* l2_bk = (const float*)d_in[22];
    const float* l2_bv = (const float*)d_in[23];
    const float* l2_bs = (const float*)d_in[24];
    const float* l2_Wb = (const float*)d_in[25];
    const float* l3_Wq = (const float*)d_in[26];
    const float* l3_Wk = (const float*)d_in[27];
    const float* l3_Wv = (const float*)d_in[28];
    const float* l3_Ws = (const float*)d_in[29];
    const float* l3_bq = (const float*)d_in[30];
    const float* l3_bk = (const float*)d_in[31];
    const float* l3_bv = (const float*)d_in[32];
    const float* l3_bs = (const float*)d_in[33];
    const float* l3_Wb = (const float*)d_in[34];
    const float* w_omega = (const float*)d_in[35];
    const float* b_omega = (const float*)d_in[36];
    const float* u_omega = (const float*)d_in[37];
    const float* rl      = (const float*)d_in[38];

    // ---- workspace layout: per-relation buffers ----
    float* ws = (float*)d_ws;
    size_t o = 0;
    float* emb = ws + o; o += (size_t)3 * N3 * H;
    float* qs1 = ws + o; o += (size_t)3 * N1 * 512;
    float* qs2 = ws + o; o += (size_t)3 * N2 * 256;
    float* qs3 = ws + o; o += (size_t)3 * N3 * 512;
    float* ps  = ws + o; o += (size_t)3 * 64 * H;
    float* pss = ws + o; o += (size_t)3 * 64 * H;

    bf16* bws = (bf16*)(ws + o);
    size_t b = 0;
    bf16* Xg  = bws + b; b += (size_t)3 * N0 * H;
    bf16* kv1 = bws + b; b += (size_t)3 * N0 * 512;
    bf16* x1b = bws + b; b += (size_t)3 * N1 * 256;
    bf16* kv2 = bws + b; b += (size_t)3 * N1 * 256;
    bf16* x2b = bws + b; b += (size_t)3 * N2 * 128;
    bf16* kv3 = bws + b; b += (size_t)3 * N2 * 512;
    bf16* Wkv1 = bws + b; b += (size_t)3 * 512 * H;
    bf16* Wqs1 = bws + b; b += (size_t)3 * 512 * H;
    bf16* Wkv2 = bws + b; b += (size_t)3 * 256 * H;
    bf16* Wqs2 = bws + b; b += (size_t)3 * 256 * H;
    bf16* Wkv3 = bws + b; b += (size_t)3 * 512 * 128;
    bf16* Wqs3 = bws + b; b += (size_t)3 * 512 * 128;

    const float sc128 = 0.088388347648318447f;  // 1/sqrt(128)
    const float sc256 = 0.0625f;                // 1/sqrt(256)

    // ---- all weight packs, one dispatch ----
    pack_all<<<dim3(512, 3, 6), 256, 0, stream>>>(
        l1_Wk, l1_Wv, l1_Wq, l1_Ws, l2_Wk, l2_Wv, l2_Wq, l2_Ws,
        l3_Wk, l3_Wv, l3_Wq, l3_Ws, Wkv1, Wqs1, Wkv2, Wqs2, Wkv3, Wqs3);

    // ---- gather (all relations) ----
    gather_bf16<<<dim3((N0 * 32 + 255) / 256, 3), 256, 0, stream>>>(
        features, n_ids, Xg, N0);

    // ---- L1: din=256, heads=2, hc=256, N=512, K=256; 8-wave blocks, y=1 ----
    {
        int nbKV = (N0 + 63) / 64, nbQS = (N1 + 63) / 64;
        gemm_dual<256, 8><<<dim3(nbKV + nbQS, 1, 3), 512, 0, stream>>>(
            Xg, (size_t)N0 * H, Wkv1, Wqs1, l1_bk, l1_bv, l1_bq, l1_bs, 256,
            kv1, (size_t)N0 * 512, N0, qs1, (size_t)N1 * 512, N1, nbKV);
    }
    attn_gate<4, 2><<<dim3((N1 + 3) / 4, 3), 256, 0, stream>>>(
        qs1, (size_t)N1 * 512, kv1, (size_t)N0 * 512, src1, l1_Wb,
        (float*)nullptr, 0, x1b, (size_t)N1 * 256, N1, sc128);
    colstat_partial<<<dim3(64, 3), 256, 0, stream>>>(x1b, (size_t)N1 * 256, N1, ps, pss);
    colfinal_norm_elu<<<dim3(128, 3), 256, 0, stream>>>(ps, pss, x1b, (size_t)N1 * 256, N1);

    // ---- L2: din=256, heads=1, hc=128, N=256, K=256; 4-wave blocks ----
    {
        int nbKV = (N1 + 63) / 64, nbQS = (N2 + 63) / 64;
        gemm_dual<256, 4><<<dim3(nbKV + nbQS, 1, 3), 256, 0, stream>>>(
            x1b, (size_t)N1 * 256, Wkv2, Wqs2, l2_bk, l2_bv, l2_bq, l2_bs, 128,
            kv2, (size_t)N1 * 256, N1, qs2, (size_t)N2 * 256, N2, nbKV);
    }
    attn_gate<2, 1><<<dim3((N2 + 3) / 4, 3), 256, 0, stream>>>(
        qs2, (size_t)N2 * 256, kv2, (size_t)N1 * 256, src2, l2_Wb,
        (float*)nullptr, 0, x2b, (size_t)N2 * 128, N2, sc128);

    // ---- L3: din=128, heads=1, hc=256, N=512, K=128; 4-wave blocks, y=2 ----
    {
        int nbKV = (N2 + 63) / 64, nbQS = (N3 + 63) / 64;
        gemm_dual<128, 4><<<dim3(nbKV + nbQS, 2, 3), 256, 0, stream>>>(
            x2b, (size_t)N2 * 128, Wkv3, Wqs3, l3_bk, l3_bv, l3_bq, l3_bs, 256,
            kv3, (size_t)N2 * 512, N2, qs3, (size_t)N3 * 512, N3, nbKV);
    }
    attn_gate<4, 1><<<dim3((N3 + 3) / 4, 3), 256, 0, stream>>>(
        qs3, (size_t)N3 * 512, kv3, (size_t)N2 * 512, src3, l3_Wb,
        emb, (size_t)N3 * H, (bf16*)nullptr, 0, N3, sc256);

    semantic_kernel<<<N3, 256, 0, stream>>>(emb, w_omega, b_omega, u_omega, rl, (float*)d_out);
}